// Round 7
// baseline (2041.469 us; speedup 1.0000x reference)
//
#include <hip/hip_runtime.h>
#include <hip/hip_bf16.h>

// Problem constants
#define S_LEN  1024
#define B_SZ   32
#define IN_DIM 3072
#define HID    256
#define NHEAD  16
#define HDIM   16
#define DFF    1024
#define NLAYER 4
#define NCLS   1623
#define EMB_D  10
#define MROWS  (S_LEN * B_SZ)   // 32768
#define QSTRIDE 52               // padded per-step qkvb stride (16B aligned)
#define CHUNK  32                // scan steps staged per LDS chunk

using bf16   = __hip_bfloat16;
using short8 = __attribute__((ext_vector_type(8))) short;
using f32x4  = __attribute__((ext_vector_type(4))) float;

#define GLOAD16(g, l) __builtin_amdgcn_global_load_lds(                        \
    (const __attribute__((address_space(1))) void*)(g),                        \
    (__attribute__((address_space(3))) void*)(l), 16, 0, 0)

// ---------------------------------------------------------------------------
// bf16 MFMA GEMM: C[M,N] = A[M,K]@W[N,K]^T.  BM=BN=128, BK=32, 256 thr/4 waves,
// each wave a 64x64 quadrant (4x4 frags of 16x16x32). K multiple of 32.
// W buffers padded to 128-multiple rows. FLAGS: 1 bias, 2 relu, 4 residual(fp32),
// 8 bf16-out, 16 permuted qkvb store (fp32, (b,h,s,52) layout).
// ---------------------------------------------------------------------------
template<int FLAGS>
__global__ __launch_bounds__(256) void mgemm(
    const bf16* __restrict__ A, const bf16* __restrict__ W,
    const float* __restrict__ bias, const float* R, void* C,
    int N, int K, int Wld)
{
    __shared__ bf16 sA[2][128 * 32];
    __shared__ bf16 sB[2][128 * 32];
    const int t    = threadIdx.x;
    const int lane = t & 63;
    const int wid  = t >> 6;
    const int wr   = wid >> 1, wc = wid & 1;
    const long bm  = (long)blockIdx.x * 128;
    const int  bn  = blockIdx.y * 128;
    const int  fr  = lane & 15;        // frag row/col
    const int  fg  = lane >> 4;        // k-group
    const int  row0 = t >> 2;          // staging row (0..63), +64 for 2nd issue
    const int  kq0  = (t & 3) << 3;    // staging k offset (elems)

    f32x4 acc[4][4];
#pragma unroll
    for (int m = 0; m < 4; ++m)
#pragma unroll
        for (int n = 0; n < 4; ++n)
#pragma unroll
            for (int r = 0; r < 4; ++r) acc[m][n][r] = 0.f;

    const int nkt = K >> 5;

    auto stage = [&](int buf, int kt) {
        const int k0 = kt << 5;
        GLOAD16(A + (bm + row0)      * (long)K   + k0 + kq0, &sA[buf][(t      ) * 8]);
        GLOAD16(A + (bm + row0 + 64) * (long)K   + k0 + kq0, &sA[buf][(t + 256) * 8]);
        GLOAD16(W + (long)(bn + row0)      * Wld + k0 + kq0, &sB[buf][(t      ) * 8]);
        GLOAD16(W + (long)(bn + row0 + 64) * Wld + k0 + kq0, &sB[buf][(t + 256) * 8]);
    };

    stage(0, 0);
    __syncthreads();
    for (int kt = 0; kt < nkt; ++kt) {
        const int cur = kt & 1;
        if (kt + 1 < nkt) stage(cur ^ 1, kt + 1);
        short8 af[4], bg[4];
#pragma unroll
        for (int m = 0; m < 4; ++m)
            af[m] = *(const short8*)&sA[cur][(wr * 64 + m * 16 + fr) * 32 + fg * 8];
#pragma unroll
        for (int n = 0; n < 4; ++n)
            bg[n] = *(const short8*)&sB[cur][(wc * 64 + n * 16 + fr) * 32 + fg * 8];
#pragma unroll
        for (int m = 0; m < 4; ++m)
#pragma unroll
            for (int n = 0; n < 4; ++n)
                acc[m][n] = __builtin_amdgcn_mfma_f32_16x16x32_bf16(
                    af[m], bg[n], acc[m][n], 0, 0, 0);
        __syncthreads();
    }

    // Epilogue. C/D layout (HW-verified): col = lane&15, row = (lane>>4)*4+reg.
    float bs[4];
#pragma unroll
    for (int n = 0; n < 4; ++n) {
        const int c = bn + wc * 64 + n * 16 + fr;
        bs[n] = ((FLAGS & 1) && c < N) ? bias[c] : 0.f;
    }
#pragma unroll
    for (int m = 0; m < 4; ++m) {
#pragma unroll
        for (int n = 0; n < 4; ++n) {
            const int c = bn + wc * 64 + n * 16 + fr;
            if (c < N) {
#pragma unroll
                for (int r = 0; r < 4; ++r) {
                    const long rw = bm + wr * 64 + m * 16 + fg * 4 + r;
                    float v = acc[m][n][r] + bs[n];
                    if (FLAGS & 2) v = fmaxf(v, 0.f);
                    if (FLAGS & 4) v += R[rw * N + c];
                    if (FLAGS & 16) {
                        const int s = (int)(rw >> 5), b = (int)(rw & 31);
                        const int hh = c / 49, cc = c - hh * 49;
                        ((float*)C)[((long)(b * 16 + hh) * 1024 + s) * QSTRIDE + cc] = v;
                    } else if (FLAGS & 8) {
                        ((bf16*)C)[rw * N + c] = __float2bfloat16(v);
                    } else {
                        ((float*)C)[rw * N + c] = v;
                    }
                }
            }
        }
    }
}

// ---------------------------------------------------------------------------
// fp32 -> bf16 bulk convert, count divisible by 8.
// ---------------------------------------------------------------------------
__global__ __launch_bounds__(256) void cvt8(const float* __restrict__ s,
                                            bf16* __restrict__ d, long n8)
{
    for (long i = (long)blockIdx.x * 256 + threadIdx.x; i < n8;
         i += (long)gridDim.x * 256) {
        const float4 a = ((const float4*)s)[i * 2];
        const float4 b = ((const float4*)s)[i * 2 + 1];
        alignas(16) bf16 t[8];
        t[0] = __float2bfloat16(a.x); t[1] = __float2bfloat16(a.y);
        t[2] = __float2bfloat16(a.z); t[3] = __float2bfloat16(a.w);
        t[4] = __float2bfloat16(b.x); t[5] = __float2bfloat16(b.y);
        t[6] = __float2bfloat16(b.z); t[7] = __float2bfloat16(b.w);
        ((short8*)d)[i] = *(const short8*)t;
    }
}

// ---------------------------------------------------------------------------
// fp32 [rows][cols] -> bf16 [prows][pcols], zero-padded.
// ---------------------------------------------------------------------------
__global__ __launch_bounds__(256) void cvtpad(const float* __restrict__ s,
                                              bf16* __restrict__ d,
                                              int rows, int cols, int prows, int pcols)
{
    const long tot = (long)prows * pcols;
    for (long i = (long)blockIdx.x * 256 + threadIdx.x; i < tot;
         i += (long)gridDim.x * 256) {
        const int r = (int)(i / pcols), c = (int)(i - (long)r * pcols);
        d[i] = (r < rows && c < cols) ? __float2bfloat16(s[(long)r * cols + c])
                                      : __float2bfloat16(0.f);
    }
}

// ---------------------------------------------------------------------------
// LayerNorm(256) -> bf16. One wave per row, 4 rows/block.
// ---------------------------------------------------------------------------
__global__ __launch_bounds__(256) void ln_b(
    const float* __restrict__ x, const float* __restrict__ g,
    const float* __restrict__ b, bf16* __restrict__ y)
{
    const int wave = threadIdx.x >> 6, lane = threadIdx.x & 63;
    const long row = (long)(blockIdx.x << 2) + wave;
    const float4 v = ((const float4*)(x + row * HID))[lane];
    float s = v.x + v.y + v.z + v.w;
#pragma unroll
    for (int m = 32; m; m >>= 1) s += __shfl_xor(s, m);
    const float mean = s * (1.f / 256.f);
    const float d0 = v.x - mean, d1 = v.y - mean, d2 = v.z - mean, d3 = v.w - mean;
    float ss = d0 * d0 + d1 * d1 + d2 * d2 + d3 * d3;
#pragma unroll
    for (int m = 32; m; m >>= 1) ss += __shfl_xor(ss, m);
    const float inv = rsqrtf(ss * (1.f / 256.f) + 1e-5f);
    const float4 gg = ((const float4*)g)[lane];
    const float4 bb = ((const float4*)b)[lane];
    alignas(8) bf16 t[4];
    t[0] = __float2bfloat16(fmaf(d0 * inv, gg.x, bb.x));
    t[1] = __float2bfloat16(fmaf(d1 * inv, gg.y, bb.y));
    t[2] = __float2bfloat16(fmaf(d2 * inv, gg.z, bb.z));
    t[3] = __float2bfloat16(fmaf(d3 * inv, gg.w, bb.w));
    *(ushort4*)((unsigned short*)y + row * HID + lane * 4) = *(const ushort4*)t;
}

// ---------------------------------------------------------------------------
// Concat: hcat[row] = [abuf[row] (256 bf16), bf16(emb[fb[row]]) (10), 0 (22)]
// ---------------------------------------------------------------------------
__global__ __launch_bounds__(64) void concat_b(
    const bf16* __restrict__ ab, const float* __restrict__ emb,
    const int* __restrict__ fb, bf16* __restrict__ hcat)
{
    const long row = blockIdx.x;
    const int lane = threadIdx.x;
    const ushort4 v = ((const ushort4*)(ab + row * HID))[lane];
    ((ushort4*)(hcat + row * 288))[lane] = v;
    if (lane < 32) {
        bf16 val = (lane < EMB_D)
            ? __float2bfloat16(emb[(long)fb[row] * EMB_D + lane])
            : __float2bfloat16(0.f);
        hcat[row * 288 + 256 + lane] = val;
    }
}

// ---------------------------------------------------------------------------
// Delta-rule scan v4: one wave per 4 chains (lane = chain c=l>>4, v-col vi=l&15);
// lane holds W[:,vi] (16 regs) -> no cross-lane ops. Chunks staged to LDS via
// global_load_lds; softmax/sigmoid fused in-LDS per chunk.
// New vs v3: (a) 4-deep static register pipeline over steps (sets A-D) so the
// serial fmaf chain overlaps the next steps' ds_reads; (b) counted wait
// vmcnt(32): retires the 26 chunk loads (always oldest) while leaving the
// <=32 output stores in flight -- no drain stalls, robust to spills.
// ---------------------------------------------------------------------------
#define LOADQK(S, slx) do {                                                    \
    const float* _p = base + ((slx) * 4 + c) * 52;                             \
    S##q0 = *(const float4*)(_p +  0);                                         \
    S##q1 = *(const float4*)(_p +  4);                                         \
    S##q2 = *(const float4*)(_p +  8);                                         \
    S##q3 = *(const float4*)(_p + 12);                                         \
    S##k0 = *(const float4*)(_p + 16);                                         \
    S##k1 = *(const float4*)(_p + 20);                                         \
    S##k2 = *(const float4*)(_p + 24);                                         \
    S##k3 = *(const float4*)(_p + 28);                                         \
    S##vt = _p[32 + vi];                                                       \
    S##bt = _p[48];                                                            \
} while (0)

#define STEP(S, sg) do {                                                       \
    float _pa = fmaf(W[3],  S##k0.w, fmaf(W[2],  S##k0.z, fmaf(W[1],  S##k0.y, W[0]  * S##k0.x))); \
    float _pb = fmaf(W[7],  S##k1.w, fmaf(W[6],  S##k1.z, fmaf(W[5],  S##k1.y, W[4]  * S##k1.x))); \
    float _pc = fmaf(W[11], S##k2.w, fmaf(W[10], S##k2.z, fmaf(W[9],  S##k2.y, W[8]  * S##k2.x))); \
    float _pd = fmaf(W[15], S##k3.w, fmaf(W[14], S##k3.z, fmaf(W[13], S##k3.y, W[12] * S##k3.x))); \
    const float _vold = (_pa + _pb) + (_pc + _pd);                             \
    const float _dv = S##bt * (S##vt - _vold);                                 \
    W[0]  = fmaf(S##k0.x, _dv, W[0]);  W[1]  = fmaf(S##k0.y, _dv, W[1]);       \
    W[2]  = fmaf(S##k0.z, _dv, W[2]);  W[3]  = fmaf(S##k0.w, _dv, W[3]);       \
    W[4]  = fmaf(S##k1.x, _dv, W[4]);  W[5]  = fmaf(S##k1.y, _dv, W[5]);       \
    W[6]  = fmaf(S##k1.z, _dv, W[6]);  W[7]  = fmaf(S##k1.w, _dv, W[7]);       \
    W[8]  = fmaf(S##k2.x, _dv, W[8]);  W[9]  = fmaf(S##k2.y, _dv, W[9]);       \
    W[10] = fmaf(S##k2.z, _dv, W[10]); W[11] = fmaf(S##k2.w, _dv, W[11]);      \
    W[12] = fmaf(S##k3.x, _dv, W[12]); W[13] = fmaf(S##k3.y, _dv, W[13]);      \
    W[14] = fmaf(S##k3.z, _dv, W[14]); W[15] = fmaf(S##k3.w, _dv, W[15]);      \
    float _oa = fmaf(W[3],  S##q0.w, fmaf(W[2],  S##q0.z, fmaf(W[1],  S##q0.y, W[0]  * S##q0.x))); \
    float _ob = fmaf(W[7],  S##q1.w, fmaf(W[6],  S##q1.z, fmaf(W[5],  S##q1.y, W[4]  * S##q1.x))); \
    float _oc = fmaf(W[11], S##q2.w, fmaf(W[10], S##q2.z, fmaf(W[9],  S##q2.y, W[8]  * S##q2.x))); \
    float _od = fmaf(W[15], S##q3.w, fmaf(W[14], S##q3.z, fmaf(W[13], S##q3.y, W[12] * S##q3.x))); \
    const float _ov = (_oa + _ob) + (_oc + _od);                               \
    po[(long)(sg) * (B_SZ * HID)] = __float2bfloat16(_ov);                     \
} while (0)

__global__ __launch_bounds__(64) void scan4(
    const float* __restrict__ qkvb, bf16* __restrict__ o)
{
    __shared__ float lds[2][4 * CHUNK * 52];   // 2 x 26624 B
    const int lane = threadIdx.x;
    const int c  = lane >> 4;        // chain within block
    const int vi = lane & 15;        // v column
    const int bh0 = blockIdx.x << 2; // 4 chains per block
    const int chain = bh0 + c;
    const int b = chain >> 4, hh = chain & 15;

    bf16* po = o + (long)b * HID + hh * HDIM + vi;

    // stage chunk ch into lds[buf]: 26 issues x 64 lanes x 16B
    auto stage = [&](int buf, int ch) {
#pragma unroll
        for (int i = 0; i < 26; ++i) {
            const int slot = i * 64 + lane;        // float4 slot in LDS
            const int row  = slot / 13;            // 0..127 = s_local*4 + cc
            const int f4   = slot - row * 13;
            const int cc   = row & 3, sl = row >> 2;
            const float* src = qkvb
                + (((long)(bh0 + cc) << 10) + ch * CHUNK + sl) * QSTRIDE + f4 * 4;
            GLOAD16(src, &lds[buf][i * 256]);
        }
    };

    float W[16];
#pragma unroll
    for (int j = 0; j < 16; ++j) W[j] = 0.f;

    stage(0, 0);
    asm volatile("s_waitcnt vmcnt(0)" ::: "memory");
    const int nch = S_LEN / CHUNK;
    for (int ch = 0; ch < nch; ++ch) {
        const int buf = ch & 1;
        // chunk ch's 26 loads are the oldest outstanding vmem ops; <=32 output
        // stores (newer) may stay in flight.
        asm volatile("s_waitcnt vmcnt(32)" ::: "memory");

        // fused prep: softmax q[0:16], k[16:32], sigmoid beta[48]; 2 rows/lane
        float* base = lds[buf];
#pragma unroll
        for (int rr = 0; rr < 2; ++rr) {
            float* p = base + (rr * 64 + lane) * 52;
            float4 q[4], k[4];
#pragma unroll
            for (int i = 0; i < 4; ++i) {
                q[i] = *(float4*)(p + i * 4);
                k[i] = *(float4*)(p + 16 + i * 4);
            }
            float qm = -1e30f, km = -1e30f;
#pragma unroll
            for (int i = 0; i < 4; ++i) {
                qm = fmaxf(qm, fmaxf(fmaxf(q[i].x, q[i].y), fmaxf(q[i].z, q[i].w)));
                km = fmaxf(km, fmaxf(fmaxf(k[i].x, k[i].y), fmaxf(k[i].z, k[i].w)));
            }
            float qs = 0.f, ks = 0.f;
#pragma unroll
            for (int i = 0; i < 4; ++i) {
                q[i].x = __expf(q[i].x - qm); q[i].y = __expf(q[i].y - qm);
                q[i].z = __expf(q[i].z - qm); q[i].w = __expf(q[i].w - qm);
                qs += q[i].x + q[i].y + q[i].z + q[i].w;
                k[i].x = __expf(k[i].x - km); k[i].y = __expf(k[i].y - km);
                k[i].z = __expf(k[i].z - km); k[i].w = __expf(k[i].w - km);
                ks += k[i].x + k[i].y + k[i].z + k[i].w;
            }
            const float qi = 1.f / qs, ki = 1.f / ks;
#pragma unroll
            for (int i = 0; i < 4; ++i) {
                q[i].x *= qi; q[i].y *= qi; q[i].z *= qi; q[i].w *= qi;
                k[i].x *= ki; k[i].y *= ki; k[i].z *= ki; k[i].w *= ki;
                *(float4*)(p + i * 4) = q[i];
                *(float4*)(p + 16 + i * 4) = k[i];
            }
            p[48] = 1.f / (1.f + __expf(-p[48]));
        }
        asm volatile("s_waitcnt lgkmcnt(0)" ::: "memory"); // prep visible wave-wide

        // prefetch next chunk now: its HBM/L2 latency hides under rec below
        if (ch + 1 < nch) stage(buf ^ 1, ch + 1);

        // recurrence over CHUNK steps, 4-deep static register pipeline
        const int sg0 = ch * CHUNK;
        float4 Aq0, Aq1, Aq2, Aq3, Ak0, Ak1, Ak2, Ak3;
        float4 Bq0, Bq1, Bq2, Bq3, Bk0, Bk1, Bk2, Bk3;
        float4 Cq0, Cq1, Cq2, Cq3, Ck0, Ck1, Ck2, Ck3;
        float4 Dq0, Dq1, Dq2, Dq3, Dk0, Dk1, Dk2, Dk3;
        float Avt, Abt, Bvt, Bbt, Cvt, Cbt, Dvt, Dbt;
        LOADQK(A, 0);
        LOADQK(B, 1);
        LOADQK(C, 2);
#pragma unroll
        for (int sl = 0; sl < CHUNK; sl += 4) {
            LOADQK(D, sl + 3);
            STEP(A, sg0 + sl);
            if (sl + 4 < CHUNK) LOADQK(A, sl + 4);
            STEP(B, sg0 + sl + 1);
            if (sl + 5 < CHUNK) LOADQK(B, sl + 5);
            STEP(C, sg0 + sl + 2);
            if (sl + 6 < CHUNK) LOADQK(C, sl + 6);
            STEP(D, sg0 + sl + 3);
        }
    }
}

// ---------------------------------------------------------------------------
extern "C" void kernel_launch(void* const* d_in, const int* in_sizes, int n_in,
                              void* d_out, int out_size, void* d_ws, size_t ws_size,
                              hipStream_t stream)
{
    const float* x      = (const float*)d_in[0];
    const int*   fb     = (const int*)  d_in[1];
    const float* fc1_w  = (const float*)d_in[2];
    const float* fc1_b  = (const float*)d_in[3];
    const float* emb    = (const float*)d_in[4];
    const float* proj_w = (const float*)d_in[5];
    const float* proj_b = (const float*)d_in[6];
    const float* ln1_g  = (const float*)d_in[7];
    const float* ln1_b  = (const float*)d_in[8];
    const float* slow_w = (const float*)d_in[9];
    const float* out_w  = (const float*)d_in[10];
    const float* ln2_g  = (const float*)d_in[11];
    const float* ln2_b  = (const float*)d_in[12];
    const float* ff1_w  = (const float*)d_in[13];
    const float* ff1_b  = (const float*)d_in[14];
    const float* ff2_w  = (const float*)d_in[15];
    const float* ff2_b  = (const float*)d_in[16];
    const float* outl_w = (const float*)d_in[17];
    const float* outl_b = (const float*)d_in[18];

    // ---- workspace layout (59.5 MB) ----
    char* wp = (char*)d_ws;
    float* h    = (float*)wp;                 wp += (size_t)MROWS * HID * 4;   // 33.5MB
    bf16*  abuf = (bf16*)wp;                  wp += (size_t)MROWS * HID * 2;   // 16.8MB
    bf16*  fc1b = (bf16*)wp;                  wp += (size_t)HID * IN_DIM * 2;
    bf16*  projb= (bf16*)wp;                  wp += (size_t)HID * 288 * 2;
    bf16*  slowb= (bf16*)wp;                  wp += (size_t)NLAYER * 896 * HID * 2;
    bf16*  outwb= (bf16*)wp;                  wp += (size_t)NLAYER * HID * HID * 2;
    bf16*  ff1b = (bf16*)wp;                  wp += (size_t)NLAYER * DFF * HID * 2;
    bf16*  ff2b = (bf16*)wp;                  wp += (size_t)NLAYER * HID * DFF * 2;
    bf16*  outlb= (bf16*)wp;                  wp += (size_t)1664 * HID * 2;

    // ---- d_out scratch (212.9 MB), sequentially reused ----
    bf16*  xb   = (bf16*)d_out;               // 201.3MB, dead after fc1
    bf16*  hcat = (bf16*)d_out;               // 18.9MB, dead after proj
    float* qkvb = (float*)d_out;              // 109.1MB, dead after scan
    bf16*  hff  = (bf16*)d_out;               // 67.1MB, dead after ff2

    const dim3 blk(256);

    // ---- weight/input conversions (re-done every launch; deterministic) ----
    cvt8<<<dim3(4096), blk, 0, stream>>>(x, xb, (long)MROWS * IN_DIM / 8);
    cvt8<<<dim3(384),  blk, 0, stream>>>(fc1_w, fc1b, (long)HID * IN_DIM / 8);
    cvtpad<<<dim3(288), blk, 0, stream>>>(proj_w, projb, HID, HID + EMB_D, HID, 288);
    for (int l = 0; l < NLAYER; ++l)
        cvtpad<<<dim3(896), blk, 0, stream>>>(slow_w + (size_t)l * 784 * HID,
                                              slowb + (size_t)l * 896 * HID,
                                              784, HID, 896, HID);
    cvt8<<<dim3(128), blk, 0, stream>>>(out_w, outwb, (long)NLAYER * HID * HID / 8);
    cvt8<<<dim3(512), blk, 0, stream>>>(ff1_w, ff1b, (long)NLAYER * DFF * HID / 8);
    cvt8<<<dim3(512), blk, 0, stream>>>(ff2_w, ff2b, (long)NLAYER * HID * DFF / 8);
    cvtpad<<<dim3(1664), blk, 0, stream>>>(outl_w, outlb, NCLS, HID, 1664, HID);

    // fc1: abuf = bf16(x @ fc1_w^T + b)    N=256 K=3072
    mgemm<9><<<dim3(256, 2), blk, 0, stream>>>(xb, fc1b, fc1_b, nullptr, abuf,
                                               HID, IN_DIM, IN_DIM);
    // hcat = [abuf, emb[fb], 0-pad]  (K padded to 288)
    concat_b<<<dim3(MROWS), dim3(64), 0, stream>>>(abuf, emb, fb, hcat);
    // proj: h = hcat @ proj_w^T + b        N=256 K=288(266+pad)
    mgemm<1><<<dim3(256, 2), blk, 0, stream>>>(hcat, projb, proj_b, nullptr, h,
                                               HID, 288, 288);

    for (int l = 0; l < NLAYER; ++l) {
        ln_b<<<dim3(MROWS / 4), blk, 0, stream>>>(h, ln1_g + l * HID, ln1_b + l * HID, abuf);
        // qkvb (permuted (b,h,s,52) fp32, RAW — softmax fused into scan4)
        mgemm<16><<<dim3(256, 7), blk, 0, stream>>>(abuf, slowb + (size_t)l * 896 * HID,
                                                    nullptr, nullptr, qkvb, 784, HID, HID);
        scan4<<<dim3(B_SZ * NHEAD / 4), dim3(64), 0, stream>>>(qkvb, abuf);
        // h += o @ out_w^T                  N=256 K=256
        mgemm<4><<<dim3(256, 2), blk, 0, stream>>>(abuf, outwb + (size_t)l * HID * HID,
                                                   nullptr, h, h, HID, HID, HID);
        ln_b<<<dim3(MROWS / 4), blk, 0, stream>>>(h, ln2_g + l * HID, ln2_b + l * HID, abuf);
        // hff = bf16(relu(y @ ff1^T + b1))  N=1024 K=256
        mgemm<11><<<dim3(256, 8), blk, 0, stream>>>(abuf, ff1b + (size_t)l * DFF * HID,
                                                    ff1_b + l * DFF, nullptr, hff,
                                                    DFF, HID, HID);
        // h += hff @ ff2^T + b2             N=256 K=1024
        mgemm<5><<<dim3(256, 2), blk, 0, stream>>>(hff, ff2b + (size_t)l * HID * DFF,
                                                   ff2_b + l * HID, h, h, HID, DFF, DFF);
    }
    // final: abuf = bf16(h); out = abuf @ outl_w^T + b  (fp32, N=1623 K=256)
    cvt8<<<dim3(1024), blk, 0, stream>>>(h, abuf, (long)MROWS * HID / 8);
    mgemm<1><<<dim3(256, 13), blk, 0, stream>>>(abuf, outlb, outl_b, nullptr, d_out,
                                                NCLS, HID, HID);
}